// Round 5
// baseline (255.586 us; speedup 1.0000x reference)
//
#include <hip/hip_runtime.h>

// EnhanceCls: 2 segmented MLP passes (GEMM w/ fused f32->bf16 staging + fused
// BN-stats, bf16 H chain, XCD-aware grid) + prototype enhancement + feature
// walk (rank-based top-k). C=5 S=5 Q=75 P=196 D=384 K=30.

#define CC 5
#define SS 5
#define QQ 75
#define PP 196
#define DD 384
#define KK 30
#define QP (QQ * PP)   // 14700

typedef short bf16x8 __attribute__((ext_vector_type(8)));
typedef float f32x4  __attribute__((ext_vector_type(4)));
typedef unsigned short us16x4 __attribute__((ext_vector_type(4)));
typedef unsigned short us16x8 __attribute__((ext_vector_type(8)));
typedef unsigned short u16;

struct SegDesc { int b0, b1; float invM; };

__device__ __forceinline__ u16 f2bf(float f) {
    unsigned u = __float_as_uint(f);
    unsigned r = (u + 0x7fffu + ((u >> 16) & 1u)) >> 16;
    return (u16)r;
}
__device__ __forceinline__ float bf2f(u16 h) {
    return __uint_as_float((unsigned)h << 16);
}

__device__ __forceinline__ void lds_load16(const u16* g, u16* s) {
    __builtin_amdgcn_global_load_lds(
        (const __attribute__((address_space(1))) unsigned int*)g,
        (__attribute__((address_space(3))) unsigned int*)s, 16, 0, 0);
}

// XCD-aware decode: bid = g*24 + n*8 + (m%8) so the 3 n-blocks of one m-block
// share bid%8 (same XCD) -> A-tile re-reads hit that XCD's L2.
__device__ __forceinline__ bool grid_decode(int mb, int& mblk, int& nb) {
    int bid = blockIdx.x;
    int g = bid / 24, t24 = bid - g * 24;
    nb = t24 >> 3;
    mblk = g * 8 + (t24 & 7);
    return mblk < mb;
}

// ---- weight prep: 4 matrices, Wt[m][n*384+k] = bf16(W[m][k*384+n]) ----
__global__ void prep_w4(const float* __restrict__ W0, const float* __restrict__ W1,
                        const float* __restrict__ W2, const float* __restrict__ W3,
                        u16* __restrict__ Wt) {
    int idx = blockIdx.x * 256 + threadIdx.x;      // 4 * 147456
    int m = idx / (DD * DD);
    int rem = idx - m * (DD * DD);
    int n = rem / DD, k = rem - n * DD;
    const float* W = (m == 0) ? W0 : (m == 1) ? W1 : (m == 2) ? W2 : W3;
    Wt[idx] = f2bf(W[k * DD + n]);
}

// ---- GEMM1: H(bf16) = bf16(A_f32) * B, A read from up to 3 f32 segment
// sources with zero row-padding, converted during reg-staging. Fused stats. ----
__global__ __launch_bounds__(256) void gemmF(const float* __restrict__ s0p,
                                             const float* __restrict__ s1p,
                                             const float* __restrict__ s2p,
                                             int rb0, int rb1, int M0, int M1, int M2,
                                             const u16* __restrict__ Bt,
                                             u16* __restrict__ H,
                                             float* __restrict__ partial, int mb) {
    __shared__ __align__(16) u16 As[128 * 64];
    __shared__ __align__(16) u16 Bs[128 * 64];
    __shared__ float sred[2][2][64][2];
    int mblk, nb;
    if (!grid_decode(mb, mblk, nb)) return;
    const int m0 = mblk * 128, n0 = nb * 128;
    const int tid = threadIdx.x;
    const int w = tid >> 6, l = tid & 63;
    const int wr = w >> 1, wc = w & 1;

    const int seg = (m0 >= rb0) + (m0 >= rb1);
    const float* src = seg == 0 ? s0p : seg == 1 ? s1p : s2p;
    const int segbase = seg == 0 ? 0 : seg == 1 ? rb0 : rb1;
    const int Mseg = seg == 0 ? M0 : seg == 1 ? M1 : M2;
    const int rloc0 = m0 - segbase;

    f32x4 acc[4][4];
#pragma unroll
    for (int i = 0; i < 4; ++i)
#pragma unroll
        for (int j = 0; j < 4; ++j) acc[i][j] = f32x4{0.f, 0.f, 0.f, 0.f};

    int rowg[4], kplog[4], kpsw[4];
#pragma unroll
    for (int i = 0; i < 4; ++i) {
        int c = (i * 4096 + w * 1024 + l * 16) >> 4;  // 16B chunk index
        int row = c >> 3, kp = c & 7;
        rowg[i] = row;
        kplog[i] = kp;
        kpsw[i] = kp ^ (row & 7);
    }

    for (int kt = 0; kt < 6; ++kt) {
        const int k0 = kt * 64;
        // B: async global->LDS (bf16, pre-swizzled source chunks)
#pragma unroll
        for (int i = 0; i < 4; ++i)
            lds_load16(Bt + (size_t)(n0 + rowg[i]) * DD + k0 + kpsw[i] * 8, &Bs[i * 2048 + w * 512]);
        // A: reg-stage f32 -> bf16 with zero padding, swizzled ds_write
#pragma unroll
        for (int i = 0; i < 4; ++i) {
            int rl = rloc0 + rowg[i];
            f32x4 a = {0.f, 0.f, 0.f, 0.f}, b4 = {0.f, 0.f, 0.f, 0.f};
            if (rl < Mseg) {
                const f32x4* sp = (const f32x4*)(src + (size_t)rl * DD + k0 + kplog[i] * 8);
                a = sp[0]; b4 = sp[1];
            }
            us16x8 o;
            o[0] = f2bf(a.x); o[1] = f2bf(a.y); o[2] = f2bf(a.z); o[3] = f2bf(a.w);
            o[4] = f2bf(b4.x); o[5] = f2bf(b4.y); o[6] = f2bf(b4.z); o[7] = f2bf(b4.w);
            *(us16x8*)&As[rowg[i] * 64 + kpsw[i] * 8] = o;
        }
        __syncthreads();
#pragma unroll
        for (int ks = 0; ks < 2; ++ks) {
            bf16x8 af[4], bg[4];
#pragma unroll
            for (int i = 0; i < 4; ++i) {
                int rm = wr * 64 + i * 16 + (l & 15);
                af[i] = *(const bf16x8*)&As[rm * 64 + (((ks << 2) + (l >> 4)) ^ (rm & 7)) * 8];
                int rn = wc * 64 + i * 16 + (l & 15);
                bg[i] = *(const bf16x8*)&Bs[rn * 64 + (((ks << 2) + (l >> 4)) ^ (rn & 7)) * 8];
            }
#pragma unroll
            for (int i = 0; i < 4; ++i)
#pragma unroll
                for (int j = 0; j < 4; ++j)
                    acc[i][j] = __builtin_amdgcn_mfma_f32_16x16x32_bf16(af[i], bg[j], acc[i][j], 0, 0, 0);
        }
        __syncthreads();
    }
    // C write (layout: col = lane&15, row = (lane>>4)*4 + reg)
#pragma unroll
    for (int i = 0; i < 4; ++i) {
        int rb = m0 + wr * 64 + i * 16 + ((l >> 4) << 2);
#pragma unroll
        for (int j = 0; j < 4; ++j) {
            int col = n0 + wc * 64 + j * 16 + (l & 15);
#pragma unroll
            for (int r = 0; r < 4; ++r)
                H[(size_t)(rb + r) * DD + col] = f2bf(acc[i][j][r]);
        }
    }
    // fused column stats (from f32 acc)
    float ls[4], ls2[4];
#pragma unroll
    for (int j = 0; j < 4; ++j) { ls[j] = 0.f; ls2[j] = 0.f; }
#pragma unroll
    for (int i = 0; i < 4; ++i)
#pragma unroll
        for (int j = 0; j < 4; ++j)
#pragma unroll
            for (int r = 0; r < 4; ++r) {
                float v = acc[i][j][r];
                ls[j] += v; ls2[j] += v * v;
            }
#pragma unroll
    for (int j = 0; j < 4; ++j) {
        ls[j]  += __shfl_xor(ls[j], 16);  ls[j]  += __shfl_xor(ls[j], 32);
        ls2[j] += __shfl_xor(ls2[j], 16); ls2[j] += __shfl_xor(ls2[j], 32);
    }
    if ((l >> 4) == 0) {
#pragma unroll
        for (int j = 0; j < 4; ++j) {
            sred[wr][wc][j * 16 + (l & 15)][0] = ls[j];
            sred[wr][wc][j * 16 + (l & 15)][1] = ls2[j];
        }
    }
    __syncthreads();
    if (tid < 128) {
        int wcx = tid >> 6, c64 = tid & 63;
        float sa = sred[0][wcx][c64][0] + sred[1][wcx][c64][0];
        float sb = sred[0][wcx][c64][1] + sred[1][wcx][c64][1];
        size_t pi = ((size_t)mblk * DD + n0 + tid) * 2;
        partial[pi] = sa; partial[pi + 1] = sb;
    }
}

// ---- GEMM2: H(bf16) = A(bf16) * B, A via global_load_lds. Fused stats. ----
__global__ __launch_bounds__(256) void gemmS(const u16* __restrict__ A,
                                             const u16* __restrict__ Bt,
                                             u16* __restrict__ H,
                                             float* __restrict__ partial, int mb) {
    __shared__ __align__(16) u16 As[128 * 64];
    __shared__ __align__(16) u16 Bs[128 * 64];
    __shared__ float sred[2][2][64][2];
    int mblk, nb;
    if (!grid_decode(mb, mblk, nb)) return;
    const int m0 = mblk * 128, n0 = nb * 128;
    const int tid = threadIdx.x;
    const int w = tid >> 6, l = tid & 63;
    const int wr = w >> 1, wc = w & 1;

    f32x4 acc[4][4];
#pragma unroll
    for (int i = 0; i < 4; ++i)
#pragma unroll
        for (int j = 0; j < 4; ++j) acc[i][j] = f32x4{0.f, 0.f, 0.f, 0.f};

    int rowg[4], kpg[4];
#pragma unroll
    for (int i = 0; i < 4; ++i) {
        int c = (i * 4096 + w * 1024 + l * 16) >> 4;
        int row = c >> 3, kp = c & 7;
        rowg[i] = row;
        kpg[i] = kp ^ (row & 7);
    }

    for (int kt = 0; kt < 6; ++kt) {
        const int k0 = kt * 64;
#pragma unroll
        for (int i = 0; i < 4; ++i) {
            lds_load16(A  + (size_t)(m0 + rowg[i]) * DD + k0 + kpg[i] * 8, &As[i * 2048 + w * 512]);
            lds_load16(Bt + (size_t)(n0 + rowg[i]) * DD + k0 + kpg[i] * 8, &Bs[i * 2048 + w * 512]);
        }
        __syncthreads();
#pragma unroll
        for (int ks = 0; ks < 2; ++ks) {
            bf16x8 af[4], bg[4];
#pragma unroll
            for (int i = 0; i < 4; ++i) {
                int rm = wr * 64 + i * 16 + (l & 15);
                af[i] = *(const bf16x8*)&As[rm * 64 + (((ks << 2) + (l >> 4)) ^ (rm & 7)) * 8];
                int rn = wc * 64 + i * 16 + (l & 15);
                bg[i] = *(const bf16x8*)&Bs[rn * 64 + (((ks << 2) + (l >> 4)) ^ (rn & 7)) * 8];
            }
#pragma unroll
            for (int i = 0; i < 4; ++i)
#pragma unroll
                for (int j = 0; j < 4; ++j)
                    acc[i][j] = __builtin_amdgcn_mfma_f32_16x16x32_bf16(af[i], bg[j], acc[i][j], 0, 0, 0);
        }
        __syncthreads();
    }
#pragma unroll
    for (int i = 0; i < 4; ++i) {
        int rb = m0 + wr * 64 + i * 16 + ((l >> 4) << 2);
#pragma unroll
        for (int j = 0; j < 4; ++j) {
            int col = n0 + wc * 64 + j * 16 + (l & 15);
#pragma unroll
            for (int r = 0; r < 4; ++r)
                H[(size_t)(rb + r) * DD + col] = f2bf(acc[i][j][r]);
        }
    }
    float ls[4], ls2[4];
#pragma unroll
    for (int j = 0; j < 4; ++j) { ls[j] = 0.f; ls2[j] = 0.f; }
#pragma unroll
    for (int i = 0; i < 4; ++i)
#pragma unroll
        for (int j = 0; j < 4; ++j)
#pragma unroll
            for (int r = 0; r < 4; ++r) {
                float v = acc[i][j][r];
                ls[j] += v; ls2[j] += v * v;
            }
#pragma unroll
    for (int j = 0; j < 4; ++j) {
        ls[j]  += __shfl_xor(ls[j], 16);  ls[j]  += __shfl_xor(ls[j], 32);
        ls2[j] += __shfl_xor(ls2[j], 16); ls2[j] += __shfl_xor(ls2[j], 32);
    }
    if ((l >> 4) == 0) {
#pragma unroll
        for (int j = 0; j < 4; ++j) {
            sred[wr][wc][j * 16 + (l & 15)][0] = ls[j];
            sred[wr][wc][j * 16 + (l & 15)][1] = ls2[j];
        }
    }
    __syncthreads();
    if (tid < 128) {
        int wcx = tid >> 6, c64 = tid & 63;
        float sa = sred[0][wcx][c64][0] + sred[1][wcx][c64][0];
        float sb = sred[0][wcx][c64][1] + sred[1][wcx][c64][1];
        size_t pi = ((size_t)mblk * DD + n0 + tid) * 2;
        partial[pi] = sa; partial[pi + 1] = sb;
    }
}

// ---- stats finalize -> BN scale/shift form: sc = iv*g, sh = be - m*sc ----
__global__ void colfin(const float* __restrict__ partial, SegDesc s0, SegDesc s1,
                       SegDesc s2, const float* __restrict__ g,
                       const float* __restrict__ be, float* __restrict__ mstats) {
    SegDesc sd = (blockIdx.x == 0) ? s0 : (blockIdx.x == 1) ? s1 : s2;
    int t = threadIdx.x;  // 384
    float sa = 0.f, sb = 0.f;
    for (int b = sd.b0; b < sd.b1; ++b) {
        size_t pi = ((size_t)b * DD + t) * 2;
        sa += partial[pi]; sb += partial[pi + 1];
    }
    float m = sa * sd.invM;
    float var = fmaxf(sb * sd.invM - m * m, 0.f);
    float iv = rsqrtf(var + 1e-5f);
    float sc = iv * g[t];
    mstats[blockIdx.x * 768 + t] = sc;
    mstats[blockIdx.x * 768 + 384 + t] = be[t] - m * sc;
}

// ---- BN + leaky-relu -> bf16 (4-wide, up to 3 segments, pad rows -> 0) ----
__global__ void act_k(const u16* __restrict__ H, const float* __restrict__ mstats,
                      const float* __restrict__ alp, u16* __restrict__ A2,
                      int rb0, int rb1, int M0, int M1, int M2) {
    int idx4 = blockIdx.x * 256 + threadIdx.x;
    int row = idx4 / 96, cq = idx4 - row * 96, col = cq * 4;
    int seg = (row >= rb0) + (row >= rb1);
    int vr = row - (seg == 1 ? rb0 : seg == 2 ? rb1 : 0);
    int M = seg == 0 ? M0 : seg == 1 ? M1 : M2;
    us16x4 o = {0, 0, 0, 0};
    if (vr < M) {
        us16x4 h = ((const us16x4*)H)[idx4];
        const float* ms = mstats + seg * 768;
        f32x4 sc = *(const f32x4*)(ms + col);
        f32x4 sh = *(const f32x4*)(ms + 384 + col);
        float al = *alp;
        float v0 = bf2f(h.x) * sc.x + sh.x; v0 = v0 >= 0.f ? v0 : al * v0;
        float v1 = bf2f(h.y) * sc.y + sh.y; v1 = v1 >= 0.f ? v1 : al * v1;
        float v2 = bf2f(h.z) * sc.z + sh.z; v2 = v2 >= 0.f ? v2 : al * v2;
        float v3 = bf2f(h.w) * sc.w + sh.w; v3 = v3 >= 0.f ? v3 : al * v3;
        o.x = f2bf(v0); o.y = f2bf(v1); o.z = f2bf(v2); o.w = f2bf(v3);
    }
    ((us16x4*)A2)[idx4] = o;
}

// ---- final BN (+res) per segment -> f32 out, 4-wide ----
__global__ void mlp_out_k(const u16* __restrict__ H, const float* __restrict__ mstats,
                          const float* __restrict__ res0, float* __restrict__ out0,
                          const float* __restrict__ res1, float* __restrict__ out1,
                          const float* __restrict__ res2, float* __restrict__ out2,
                          int rb0, int rb1, int M0, int M1, int M2) {
    int idx4 = blockIdx.x * 256 + threadIdx.x;
    int row = idx4 / 96, cq = idx4 - row * 96, col = cq * 4;
    int seg = (row >= rb0) + (row >= rb1);
    int vr = row - (seg == 1 ? rb0 : seg == 2 ? rb1 : 0);
    int M = seg == 0 ? M0 : seg == 1 ? M1 : M2;
    const float* res = seg == 0 ? res0 : seg == 1 ? res1 : res2;
    float* outf = seg == 0 ? out0 : seg == 1 ? out1 : out2;
    f32x4 v = {0.f, 0.f, 0.f, 0.f};
    if (vr < M) {
        us16x4 h = ((const us16x4*)H)[idx4];
        const float* ms = mstats + seg * 768;
        f32x4 sc = *(const f32x4*)(ms + col);
        f32x4 sh = *(const f32x4*)(ms + 384 + col);
        v.x = bf2f(h.x) * sc.x + sh.x;
        v.y = bf2f(h.y) * sc.y + sh.y;
        v.z = bf2f(h.z) * sc.z + sh.z;
        v.w = bf2f(h.w) * sc.w + sh.w;
        if (res) {
            f32x4 r = ((const f32x4*)res)[(size_t)vr * 96 + cq];
            v.x += r.x; v.y += r.y; v.z += r.z; v.w += r.w;
        }
    }
    ((f32x4*)outf)[(size_t)vr * 96 + cq] = v;
}

// ---- dist[b][cs][p] = ||cls[cs]-patch[cs,p]||  (1 wave per row) ----
__global__ void dist_k(const float* __restrict__ epsP, const float* __restrict__ dpfP,
                       const float* __restrict__ supC, const float* __restrict__ dsupC,
                       float* __restrict__ dist) {
    int id = blockIdx.x;               // 0..9799
    int b = id / (CC * SS * PP);
    int r = id - b * (CC * SS * PP);   // cs*196+p
    int cs = r / PP;
    const float* patch = b ? dpfP : epsP;
    const float* cls = b ? dsupC : supC;
    int l = threadIdx.x;  // 64
    const float* pr = patch + (size_t)r * DD;
    const float* cr = cls + (size_t)cs * DD;
    float s = 0.f;
    for (int d = l; d < DD; d += 64) { float df = cr[d] - pr[d]; s += df * df; }
#pragma unroll
    for (int off = 32; off > 0; off >>= 1) s += __shfl_xor(s, off);
    if (l == 0) dist[id] = sqrtf(s);
}

// ---- enhance: sim = dist/(other+1e-6), rank-based top-30, mean of selected ----
__global__ void enh_k(const float* __restrict__ dist, const float* __restrict__ epsP,
                      const float* __restrict__ dpfP, const float* __restrict__ supC,
                      const float* __restrict__ dsupC, float* __restrict__ enh) {
    int id = blockIdx.x;          // 0..49 = b*25+cs
    int b = id / 25, cs = id - b * 25, c = cs / SS;
    int t = threadIdx.x;          // 384
    __shared__ float sim[PP];
    __shared__ int sidx[KK];
    const float* db = dist + b * (CC * SS * PP);
    if (t < PP) {
        float osum = 0.f;
        for (int cc = 0; cc < CC; ++cc) osum += db[cc * SS * PP + t];   // d0 (s=0) rows
        float other = osum - db[c * SS * PP + t];
        sim[t] = db[cs * PP + t] / (other + 1e-6f);
    }
    __syncthreads();
    if (t < PP) {
        float mine = sim[t];
        int cnt = 0;
        for (int p = 0; p < PP; ++p) {
            float v = sim[p];
            cnt += (v > mine) || (v == mine && p < t);
        }
        if (cnt < KK) sidx[cnt] = t;     // rank unique -> no race
    }
    __syncthreads();
    const float* patch = b ? dpfP : epsP;
    const float* cls = b ? dsupC : supC;
    float sum = 0.f;
#pragma unroll
    for (int j = 0; j < KK; ++j) sum += patch[((size_t)cs * PP + sidx[j]) * DD + t];
    enh[(size_t)id * DD + t] = 2.f * cls[(size_t)cs * DD + t] + sum * (1.f / 30.f);
}

// ---- ep[c] = mean over 10 enh rows; also prototype norms ----
__global__ void ep_k(const float* __restrict__ enh, float* __restrict__ outEp,
                     float* __restrict__ npb) {
    int t = threadIdx.x;  // 384
    __shared__ float red[DD];
    for (int c = 0; c < CC; ++c) {
        float v = 0.f;
        for (int b = 0; b < 2; ++b)
            for (int s = 0; s < SS; ++s)
                v += enh[((b * 25) + (c * SS + s)) * DD + t];
        v *= 0.1f;
        outEp[c * DD + t] = v;
        red[t] = v * v;
        __syncthreads();
        if (t < 64) {
            float s = 0.f;
            for (int i = t; i < DD; i += 64) s += red[i];
#pragma unroll
            for (int off = 32; off > 0; off >>= 1) s += __shfl_xor(s, off);
            if (t == 0) npb[c] = sqrtf(s);
        }
        __syncthreads();
    }
}

// ---- eB[c][row] = exp(cos(proto_c, patch_row) - 1): coalesced float4 reads ----
// (softmax shift by constant 1 instead of row max: cos <= 1, identical after norm)
__global__ void cos_k(const float* __restrict__ epq, const float* __restrict__ ep,
                      const float* __restrict__ npb, float* __restrict__ eB) {
    __shared__ __align__(16) float epl[CC * DD];
    __shared__ float npl[CC];
    int t = threadIdx.x;  // 256
    for (int i = t; i < CC * DD; i += 256) epl[i] = ep[i];
    if (t < CC) npl[t] = npb[t];
    __syncthreads();
    int wid = t >> 6, l = t & 63;
    int row = blockIdx.x * 4 + wid;           // 3675*4 = 14700 exactly
    const float4* rp = (const float4*)(epq + (size_t)row * DD);
    const float4* e4 = (const float4*)epl;
    float nq = 0.f, dot[CC];
#pragma unroll
    for (int c = 0; c < CC; ++c) dot[c] = 0.f;
    for (int c4 = l; c4 < DD / 4; c4 += 64) {
        float4 x = rp[c4];
        nq += x.x * x.x + x.y * x.y + x.z * x.z + x.w * x.w;
#pragma unroll
        for (int c = 0; c < CC; ++c) {
            float4 e = e4[c * (DD / 4) + c4];
            dot[c] += e.x * x.x + e.y * x.y + e.z * x.z + e.w * x.w;
        }
    }
#pragma unroll
    for (int off = 32; off > 0; off >>= 1) {
        nq += __shfl_xor(nq, off);
#pragma unroll
        for (int c = 0; c < CC; ++c) dot[c] += __shfl_xor(dot[c], off);
    }
    if (l == 0) {
        float sq = sqrtf(nq);
#pragma unroll
        for (int c = 0; c < CC; ++c)
            eB[c * QP + row] = expf(dot[c] / fmaxf(npl[c] * sq, 1e-8f) - 1.f);
    }
}

// ---- per-(c,q): normalize e, rank-based top-30, weighted-sum gather ----
__global__ void walk2_k(const float* __restrict__ eB, const float* __restrict__ epq,
                        const float* __restrict__ qcls, float* __restrict__ outp) {
    int bid = blockIdx.x;         // c*75+q
    int c = bid / QQ, q = bid - c * QQ;
    int t = threadIdx.x;          // 256
    __shared__ float wv[PP];
    __shared__ float red[256];
    __shared__ float sval[KK];
    __shared__ int sidx[KK];
    float e = 0.f;
    if (t < PP) { e = eB[c * QP + q * PP + t]; wv[t] = e; }
    red[t] = e;
    __syncthreads();
    for (int st = 128; st > 0; st >>= 1) { if (t < st) red[t] += red[t + st]; __syncthreads(); }
    float inv = 1.f / red[0];
    if (t < PP) {
        int cnt = 0;
        for (int p = 0; p < PP; ++p) {
            float v = wv[p];
            cnt += (v > e) || (v == e && p < t);
        }
        if (cnt < KK) { sval[cnt] = e * inv; sidx[cnt] = t; }
    }
    __syncthreads();
    const float* eb = epq + (size_t)q * PP * DD;
    for (int d = t; d < DD; d += 256) {
        float a = 0.f;
#pragma unroll
        for (int j = 0; j < KK; ++j) a += sval[j] * eb[(size_t)sidx[j] * DD + d];
        outp[(size_t)bid * DD + d] = 2.f * qcls[q * DD + d] + a;
    }
}

extern "C" void kernel_launch(void* const* d_in, const int* in_sizes, int n_in,
                              void* d_out, int out_size, void* d_ws, size_t ws_size,
                              hipStream_t stream) {
    const float* sup   = (const float*)d_in[0];
    const float* qcls  = (const float*)d_in[1];
    const float* dsupI = (const float*)d_in[2];
    const float* epsI  = (const float*)d_in[3];
    const float* epqI  = (const float*)d_in[4];
    const float* dpI   = (const float*)d_in[5];
    const float* daW1 = (const float*)d_in[6],  *daG1 = (const float*)d_in[8],
               * daBe1 = (const float*)d_in[9], *daAl = (const float*)d_in[10];
    const float* daW2 = (const float*)d_in[11], *daG2 = (const float*)d_in[13],
               * daBe2 = (const float*)d_in[14];
    const float* paW1 = (const float*)d_in[15], *paG1 = (const float*)d_in[17],
               * paBe1 = (const float*)d_in[18], *paAl = (const float*)d_in[19];
    const float* paW2 = (const float*)d_in[20], *paG2 = (const float*)d_in[22],
               * paBe2 = (const float*)d_in[23];

    char* ws = (char*)d_ws;
    size_t off = 0;
    auto alloc = [&](size_t b) -> void* {
        void* p = ws + off;
        off = (off + b + 255) & ~(size_t)255;
        return p;
    };
    // row geometry (all 128-aligned so GEMM blocks stay within one segment)
    const int MP_S = 128;                  // dalle_sup: 25 valid
    const int M_P = 4900,  MP_P = 4992;    // patch batches
    const int M_Q = 14700, MP_Qa = 14848;  // query patches
    const int ROWS_A  = MP_S + MP_P;               // 5120
    const int ROWS_BC = MP_P + MP_Qa + MP_P;       // 24832
    const int RB0 = MP_P, RB1 = MP_P + MP_Qa;      // 4992, 19840

    u16*   wtAll = (u16*)alloc((size_t)4 * DD * DD * 2);
    u16*   wtDa1 = wtAll;
    u16*   wtDa2 = wtAll + DD * DD;
    u16*   wtPa1 = wtAll + 2 * DD * DD;
    u16*   wtPa2 = wtAll + 3 * DD * DD;
    u16*   hbuf  = (u16*)alloc((size_t)ROWS_BC * DD * 2);
    u16*   a2buf = (u16*)alloc((size_t)ROWS_BC * DD * 2);
    float* partial = (float*)alloc((size_t)(ROWS_BC / 128) * DD * 2 * 4);
    float* mstats  = (float*)alloc(3 * 768 * 4);
    float* dalleSup = (float*)alloc((size_t)MP_S * DD * 4);
    float* dp0   = (float*)alloc((size_t)MP_P * DD * 4);
    float* epsB  = (float*)alloc((size_t)MP_P * DD * 4);
    float* epqB  = (float*)alloc((size_t)MP_Qa * DD * 4);
    float* dpfB  = (float*)alloc((size_t)MP_P * DD * 4);
    float* distB = (float*)alloc((size_t)2 * CC * SS * PP * 4);
    float* enhB  = (float*)alloc((size_t)50 * DD * 4);
    float* npB   = (float*)alloc(64);
    float* eB    = (float*)alloc((size_t)CC * QP * 4);

    // weights -> bf16 transposed (one launch)
    prep_w4<<<4 * 576, 256, 0, stream>>>(daW1, daW2, paW1, paW2, wtAll);

    // ---------- pass A (da): seg0 = dalle_emb_support(25), seg1 = dalle_patch(4900) ----------
    {
        int mb = ROWS_A / 128;                    // 40
        int nblk = ((mb + 7) / 8) * 24;           // 120
        SegDesc s0{0, 1, 1.f / 25.f}, s1{1, mb, 1.f / 4900.f}, sx{0, 0, 1.f};
        int g96 = (ROWS_A * 96) / 256;            // 1920
        gemmF<<<nblk, 256, 0, stream>>>(dsupI, dpI, nullptr, MP_S, ROWS_A,
                                        25, M_P, 0, wtDa1, hbuf, partial, mb);
        colfin<<<2, 384, 0, stream>>>(partial, s0, s1, sx, daG1, daBe1, mstats);
        act_k<<<g96, 256, 0, stream>>>(hbuf, mstats, daAl, a2buf,
                                       MP_S, ROWS_A, 25, M_P, 0);
        gemmS<<<nblk, 256, 0, stream>>>(a2buf, wtDa2, hbuf, partial, mb);
        colfin<<<2, 384, 0, stream>>>(partial, s0, s1, sx, daG2, daBe2, mstats);
        mlp_out_k<<<g96, 256, 0, stream>>>(hbuf, mstats,
                                           nullptr, dalleSup,
                                           nullptr, dp0,
                                           nullptr, nullptr,
                                           MP_S, ROWS_A, 25, M_P, 0);
    }

    // ---------- pass BC (pa): seg0 = eps(4900), seg1 = epq(14700), seg2 = dalle_patch(4900, f32 dp0) ----------
    {
        int mb = ROWS_BC / 128;                   // 194
        int nblk = ((mb + 7) / 8) * 24;           // 600
        SegDesc s0{0, RB0 / 128, 1.f / 4900.f},
                s1{RB0 / 128, RB1 / 128, 1.f / 14700.f},
                s2{RB1 / 128, mb, 1.f / 4900.f};
        int g96 = (ROWS_BC * 96) / 256;           // 9312
        gemmF<<<nblk, 256, 0, stream>>>(epsI, epqI, dp0, RB0, RB1,
                                        M_P, M_Q, M_P, wtPa1, hbuf, partial, mb);
        colfin<<<3, 384, 0, stream>>>(partial, s0, s1, s2, paG1, paBe1, mstats);
        act_k<<<g96, 256, 0, stream>>>(hbuf, mstats, paAl, a2buf,
                                       RB0, RB1, M_P, M_Q, M_P);
        gemmS<<<nblk, 256, 0, stream>>>(a2buf, wtPa2, hbuf, partial, mb);
        colfin<<<3, 384, 0, stream>>>(partial, s0, s1, s2, paG2, paBe2, mstats);
        mlp_out_k<<<g96, 256, 0, stream>>>(hbuf, mstats,
                                           epsI, epsB,
                                           epqI, epqB,
                                           dp0, dpfB,
                                           RB0, RB1, M_P, M_Q, M_P);
    }

    // ---------- enhancement ----------
    dist_k<<<2 * CC * SS * PP, 64, 0, stream>>>(epsB, dpfB, sup, dalleSup, distB);
    enh_k<<<2 * CC * SS, 384, 0, stream>>>(distB, epsB, dpfB, sup, dalleSup, enhB);

    float* outEp = (float*)d_out;
    float* outW = (float*)d_out + CC * DD;
    ep_k<<<1, 384, 0, stream>>>(enhB, outEp, npB);

    // ---------- feature walk ----------
    cos_k<<<QP / 4, 256, 0, stream>>>(epqB, outEp, npB, eB);
    walk2_k<<<CC * QQ, 256, 0, stream>>>(eB, epqB, qcls, outW);
}

// Round 7
// 234.294 us; speedup vs baseline: 1.0909x; 1.0909x over previous
//
#include <hip/hip_runtime.h>

// EnhanceCls: 2 segmented MLP passes. GEMMs use single-barrier double-buffered
// K-loop (issue-early/write-late staging); GEMM2 fuses BN+leaky into A-staging.
// C=5 S=5 Q=75 P=196 D=384 K=30.

#define CC 5
#define SS 5
#define QQ 75
#define PP 196
#define DD 384
#define KK 30
#define QP (QQ * PP)   // 14700

typedef short bf16x8 __attribute__((ext_vector_type(8)));
typedef float f32x4  __attribute__((ext_vector_type(4)));
typedef unsigned short us16x4 __attribute__((ext_vector_type(4)));
typedef unsigned short us16x8 __attribute__((ext_vector_type(8)));
typedef unsigned short u16;

struct SegDesc { int b0, b1; float invM; };

__device__ __forceinline__ u16 f2bf(float f) {
    unsigned u = __float_as_uint(f);
    unsigned r = (u + 0x7fffu + ((u >> 16) & 1u)) >> 16;
    return (u16)r;
}
__device__ __forceinline__ float bf2f(u16 h) {
    return __uint_as_float((unsigned)h << 16);
}

__device__ __forceinline__ void lds_load16(const u16* g, u16* s) {
    __builtin_amdgcn_global_load_lds(
        (const __attribute__((address_space(1))) unsigned int*)g,
        (__attribute__((address_space(3))) unsigned int*)s, 16, 0, 0);
}

// XCD-aware decode: the 3 n-blocks of one m-block share bid%8 (same XCD).
__device__ __forceinline__ bool grid_decode(int mb, int& mblk, int& nb) {
    int bid = blockIdx.x;
    int g = bid / 24, t24 = bid - g * 24;
    nb = t24 >> 3;
    mblk = g * 8 + (t24 & 7);
    return mblk < mb;
}

__device__ __forceinline__ void do_mfma(const u16* Asb, const u16* Bsb,
                                        int wr, int wc, int l, f32x4 (&acc)[4][4]) {
#pragma unroll
    for (int ks = 0; ks < 2; ++ks) {
        bf16x8 af[4], bg[4];
#pragma unroll
        for (int i = 0; i < 4; ++i) {
            int rm = wr * 64 + i * 16 + (l & 15);
            af[i] = *(const bf16x8*)&Asb[rm * 64 + (((ks << 2) + (l >> 4)) ^ (rm & 7)) * 8];
            int rn = wc * 64 + i * 16 + (l & 15);
            bg[i] = *(const bf16x8*)&Bsb[rn * 64 + (((ks << 2) + (l >> 4)) ^ (rn & 7)) * 8];
        }
#pragma unroll
        for (int i = 0; i < 4; ++i)
#pragma unroll
            for (int j = 0; j < 4; ++j)
                acc[i][j] = __builtin_amdgcn_mfma_f32_16x16x32_bf16(af[i], bg[j], acc[i][j], 0, 0, 0);
    }
}

// ---- weight prep: 4 matrices, Wt[m][n*384+k] = bf16(W[m][k*384+n]) ----
__global__ void prep_w4(const float* __restrict__ W0, const float* __restrict__ W1,
                        const float* __restrict__ W2, const float* __restrict__ W3,
                        u16* __restrict__ Wt) {
    int idx = blockIdx.x * 256 + threadIdx.x;      // 4 * 147456
    int m = idx / (DD * DD);
    int rem = idx - m * (DD * DD);
    int n = rem / DD, k = rem - n * DD;
    const float* W = (m == 0) ? W0 : (m == 1) ? W1 : (m == 2) ? W2 : W3;
    Wt[idx] = f2bf(W[k * DD + n]);
}

// ---- GEMM1: H(bf16) = bf16(A_f32) * B; dbuf single-barrier pipeline ----
__global__ __launch_bounds__(256) void gemmF(const float* __restrict__ s0p,
                                             const float* __restrict__ s1p,
                                             const float* __restrict__ s2p,
                                             int rb0, int rb1, int M0, int M1, int M2,
                                             const u16* __restrict__ Bt,
                                             u16* __restrict__ H,
                                             float* __restrict__ partial, int mb) {
    __shared__ __align__(16) u16 As[2][8192];
    __shared__ __align__(16) u16 Bs[2][8192];
    __shared__ float sred[2][2][64][2];
    int mblk, nb;
    if (!grid_decode(mb, mblk, nb)) return;
    const int m0 = mblk * 128, n0 = nb * 128;
    const int tid = threadIdx.x;
    const int w = tid >> 6, l = tid & 63;
    const int wr = w >> 1, wc = w & 1;
    const int lr8 = l >> 3, kp = l & 7, kpsw = kp ^ lr8;

    const int seg = (m0 >= rb0) + (m0 >= rb1);
    const float* src = seg == 0 ? s0p : seg == 1 ? s1p : s2p;
    const int segbase = seg == 0 ? 0 : seg == 1 ? rb0 : rb1;
    const int Mseg = seg == 0 ? M0 : seg == 1 ? M1 : M2;
    const int rloc0 = m0 - segbase;

    f32x4 acc[4][4];
#pragma unroll
    for (int i = 0; i < 4; ++i)
#pragma unroll
        for (int j = 0; j < 4; ++j) acc[i][j] = f32x4{0.f, 0.f, 0.f, 0.f};

    f32x4 ra[4], rbv[4];
    auto issueA = [&](int kta) {
#pragma unroll
        for (int i = 0; i < 4; ++i) {
            int row = i * 32 + w * 8 + lr8;
            int rl = rloc0 + row;
            ra[i] = f32x4{0.f, 0.f, 0.f, 0.f};
            rbv[i] = f32x4{0.f, 0.f, 0.f, 0.f};
            if (rl < Mseg) {
                const f32x4* sp = (const f32x4*)(src + (size_t)rl * DD + kta * 64 + kp * 8);
                ra[i] = sp[0]; rbv[i] = sp[1];
            }
        }
    };
    auto stageB = [&](int kta, int b) {
#pragma unroll
        for (int i = 0; i < 4; ++i) {
            int row = i * 32 + w * 8 + lr8;
            lds_load16(Bt + (size_t)(n0 + row) * DD + kta * 64 + kpsw * 8,
                       &Bs[b][i * 2048 + w * 512]);
        }
    };
    auto writeA = [&](int b) {
#pragma unroll
        for (int i = 0; i < 4; ++i) {
            int row = i * 32 + w * 8 + lr8;
            us16x8 o;
            o[0] = f2bf(ra[i].x); o[1] = f2bf(ra[i].y); o[2] = f2bf(ra[i].z); o[3] = f2bf(ra[i].w);
            o[4] = f2bf(rbv[i].x); o[5] = f2bf(rbv[i].y); o[6] = f2bf(rbv[i].z); o[7] = f2bf(rbv[i].w);
            *(us16x8*)&As[b][row * 64 + kpsw * 8] = o;
        }
    };

    // prologue: stage step 0
    issueA(0);
    stageB(0, 0);
    writeA(0);
    __syncthreads();
    int cur = 0;
    for (int kt = 0; kt < 5; ++kt) {
        int nxt = cur ^ 1;
        issueA(kt + 1);          // issue loads early (hide under MFMA)
        stageB(kt + 1, nxt);     // async direct-to-LDS
        do_mfma(&As[cur][0], &Bs[cur][0], wr, wc, l, acc);
        writeA(nxt);             // write-late (vmcnt wait lands after MFMA)
        __syncthreads();         // one barrier per K-step
        cur = nxt;
    }
    do_mfma(&As[cur][0], &Bs[cur][0], wr, wc, l, acc);

    // C write (layout: col = lane&15, row = (lane>>4)*4 + reg)
#pragma unroll
    for (int i = 0; i < 4; ++i) {
        int rw0 = m0 + wr * 64 + i * 16 + ((l >> 4) << 2);
#pragma unroll
        for (int j = 0; j < 4; ++j) {
            int col = n0 + wc * 64 + j * 16 + (l & 15);
#pragma unroll
            for (int r = 0; r < 4; ++r)
                H[(size_t)(rw0 + r) * DD + col] = f2bf(acc[i][j][r]);
        }
    }
    // fused column stats
    float ls[4], ls2[4];
#pragma unroll
    for (int j = 0; j < 4; ++j) { ls[j] = 0.f; ls2[j] = 0.f; }
#pragma unroll
    for (int i = 0; i < 4; ++i)
#pragma unroll
        for (int j = 0; j < 4; ++j)
#pragma unroll
            for (int r = 0; r < 4; ++r) {
                float v = acc[i][j][r];
                ls[j] += v; ls2[j] += v * v;
            }
#pragma unroll
    for (int j = 0; j < 4; ++j) {
        ls[j]  += __shfl_xor(ls[j], 16);  ls[j]  += __shfl_xor(ls[j], 32);
        ls2[j] += __shfl_xor(ls2[j], 16); ls2[j] += __shfl_xor(ls2[j], 32);
    }
    if ((l >> 4) == 0) {
#pragma unroll
        for (int j = 0; j < 4; ++j) {
            sred[wr][wc][j * 16 + (l & 15)][0] = ls[j];
            sred[wr][wc][j * 16 + (l & 15)][1] = ls2[j];
        }
    }
    __syncthreads();
    if (tid < 128) {
        int wcx = tid >> 6, c64 = tid & 63;
        float sa = sred[0][wcx][c64][0] + sred[1][wcx][c64][0];
        float sb = sred[0][wcx][c64][1] + sred[1][wcx][c64][1];
        size_t pi = ((size_t)mblk * DD + n0 + tid) * 2;
        partial[pi] = sa; partial[pi + 1] = sb;
    }
}

// ---- GEMM2: H2(bf16) = act(BN(H1)) * B; BN+leaky fused into A-staging ----
__global__ __launch_bounds__(256) void gemmA(const u16* __restrict__ Hs,
                                             int rb0, int rb1, int M0, int M1, int M2,
                                             const u16* __restrict__ Bt,
                                             const float* __restrict__ alp,
                                             const float* __restrict__ mstats,
                                             u16* __restrict__ H2,
                                             float* __restrict__ partial, int mb) {
    __shared__ __align__(16) u16 As[2][8192];
    __shared__ __align__(16) u16 Bs[2][8192];
    __shared__ float sred[2][2][64][2];
    __shared__ __align__(16) float msL[768];
    int mblk, nb;
    if (!grid_decode(mb, mblk, nb)) return;
    const int m0 = mblk * 128, n0 = nb * 128;
    const int tid = threadIdx.x;
    const int w = tid >> 6, l = tid & 63;
    const int wr = w >> 1, wc = w & 1;
    const int lr8 = l >> 3, kp = l & 7, kpsw = kp ^ lr8;

    const int seg = (m0 >= rb0) + (m0 >= rb1);
    const int segbase = seg == 0 ? 0 : seg == 1 ? rb0 : rb1;
    const int Mseg = seg == 0 ? M0 : seg == 1 ? M1 : M2;
    const int rloc0 = m0 - segbase;
    const float al = *alp;

    if (tid < 192) ((f32x4*)msL)[tid] = ((const f32x4*)(mstats + seg * 768))[tid];

    f32x4 acc[4][4];
#pragma unroll
    for (int i = 0; i < 4; ++i)
#pragma unroll
        for (int j = 0; j < 4; ++j) acc[i][j] = f32x4{0.f, 0.f, 0.f, 0.f};

    us16x8 rh[4];
    auto issueA = [&](int kta) {
#pragma unroll
        for (int i = 0; i < 4; ++i) {
            int row = i * 32 + w * 8 + lr8;
            int rl = rloc0 + row;
            rh[i] = us16x8{0, 0, 0, 0, 0, 0, 0, 0};
            if (rl < Mseg)
                rh[i] = *(const us16x8*)(Hs + (size_t)(m0 + row) * DD + kta * 64 + kp * 8);
        }
    };
    auto stageB = [&](int kta, int b) {
#pragma unroll
        for (int i = 0; i < 4; ++i) {
            int row = i * 32 + w * 8 + lr8;
            lds_load16(Bt + (size_t)(n0 + row) * DD + kta * 64 + kpsw * 8,
                       &Bs[b][i * 2048 + w * 512]);
        }
    };
    auto writeA = [&](int kta, int b) {
        int cb = kta * 64 + kp * 8;
        f32x4 scA = *(const f32x4*)&msL[cb];
        f32x4 scB = *(const f32x4*)&msL[cb + 4];
        f32x4 shA = *(const f32x4*)&msL[384 + cb];
        f32x4 shB = *(const f32x4*)&msL[384 + cb + 4];
#pragma unroll
        for (int i = 0; i < 4; ++i) {
            int row = i * 32 + w * 8 + lr8;
            int rl = rloc0 + row;
            us16x8 o = {0, 0, 0, 0, 0, 0, 0, 0};
            if (rl < Mseg) {
                float v;
                v = bf2f(rh[i][0]) * scA.x + shA.x; v = v >= 0.f ? v : al * v; o[0] = f2bf(v);
                v = bf2f(rh[i][1]) * scA.y + shA.y; v = v >= 0.f ? v : al * v; o[1] = f2bf(v);
                v = bf2f(rh[i][2]) * scA.z + shA.z; v = v >= 0.f ? v : al * v; o[2] = f2bf(v);
                v = bf2f(rh[i][3]) * scA.w + shA.w; v = v >= 0.f ? v : al * v; o[3] = f2bf(v);
                v = bf2f(rh[i][4]) * scB.x + shB.x; v = v >= 0.f ? v : al * v; o[4] = f2bf(v);
                v = bf2f(rh[i][5]) * scB.y + shB.y; v = v >= 0.f ? v : al * v; o[5] = f2bf(v);
                v = bf2f(rh[i][6]) * scB.z + shB.z; v = v >= 0.f ? v : al * v; o[6] = f2bf(v);
                v = bf2f(rh[i][7]) * scB.w + shB.w; v = v >= 0.f ? v : al * v; o[7] = f2bf(v);
            }
            *(us16x8*)&As[b][row * 64 + kpsw * 8] = o;
        }
    };

    // prologue: msL must be visible to ALL waves before writeA reads it (race
    // fix vs R6: barrier between the msL staging and its first use).
    issueA(0);
    stageB(0, 0);
    __syncthreads();      // msL visible; B0 staged
    writeA(0, 0);
    __syncthreads();      // A0 visible
    int cur = 0;
    for (int kt = 0; kt < 5; ++kt) {
        int nxt = cur ^ 1;
        issueA(kt + 1);
        stageB(kt + 1, nxt);
        do_mfma(&As[cur][0], &Bs[cur][0], wr, wc, l, acc);
        writeA(kt + 1, nxt);
        __syncthreads();
        cur = nxt;
    }
    do_mfma(&As[cur][0], &Bs[cur][0], wr, wc, l, acc);

#pragma unroll
    for (int i = 0; i < 4; ++i) {
        int rw0 = m0 + wr * 64 + i * 16 + ((l >> 4) << 2);
#pragma unroll
        for (int j = 0; j < 4; ++j) {
            int col = n0 + wc * 64 + j * 16 + (l & 15);
#pragma unroll
            for (int r = 0; r < 4; ++r)
                H2[(size_t)(rw0 + r) * DD + col] = f2bf(acc[i][j][r]);
        }
    }
    float ls[4], ls2[4];
#pragma unroll
    for (int j = 0; j < 4; ++j) { ls[j] = 0.f; ls2[j] = 0.f; }
#pragma unroll
    for (int i = 0; i < 4; ++i)
#pragma unroll
        for (int j = 0; j < 4; ++j)
#pragma unroll
            for (int r = 0; r < 4; ++r) {
                float v = acc[i][j][r];
                ls[j] += v; ls2[j] += v * v;
            }
#pragma unroll
    for (int j = 0; j < 4; ++j) {
        ls[j]  += __shfl_xor(ls[j], 16);  ls[j]  += __shfl_xor(ls[j], 32);
        ls2[j] += __shfl_xor(ls2[j], 16); ls2[j] += __shfl_xor(ls2[j], 32);
    }
    if ((l >> 4) == 0) {
#pragma unroll
        for (int j = 0; j < 4; ++j) {
            sred[wr][wc][j * 16 + (l & 15)][0] = ls[j];
            sred[wr][wc][j * 16 + (l & 15)][1] = ls2[j];
        }
    }
    __syncthreads();
    if (tid < 128) {
        int wcx = tid >> 6, c64 = tid & 63;
        float sa = sred[0][wcx][c64][0] + sred[1][wcx][c64][0];
        float sb = sred[0][wcx][c64][1] + sred[1][wcx][c64][1];
        size_t pi = ((size_t)mblk * DD + n0 + tid) * 2;
        partial[pi] = sa; partial[pi + 1] = sb;
    }
}

// ---- stats finalize -> BN scale/shift form: sc = iv*g, sh = be - m*sc ----
__global__ void colfin(const float* __restrict__ partial, SegDesc s0, SegDesc s1,
                       SegDesc s2, const float* __restrict__ g,
                       const float* __restrict__ be, float* __restrict__ mstats) {
    SegDesc sd = (blockIdx.x == 0) ? s0 : (blockIdx.x == 1) ? s1 : s2;
    int t = threadIdx.x;  // 384
    float sa = 0.f, sb = 0.f;
    for (int b = sd.b0; b < sd.b1; ++b) {
        size_t pi = ((size_t)b * DD + t) * 2;
        sa += partial[pi]; sb += partial[pi + 1];
    }
    float m = sa * sd.invM;
    float var = fmaxf(sb * sd.invM - m * m, 0.f);
    float iv = rsqrtf(var + 1e-5f);
    float sc = iv * g[t];
    mstats[blockIdx.x * 768 + t] = sc;
    mstats[blockIdx.x * 768 + 384 + t] = be[t] - m * sc;
}

// ---- final BN (+res) per segment -> f32 out, 4-wide ----
__global__ void mlp_out_k(const u16* __restrict__ H, const float* __restrict__ mstats,
                          const float* __restrict__ res0, float* __restrict__ out0,
                          const float* __restrict__ res1, float* __restrict__ out1,
                          const float* __restrict__ res2, float* __restrict__ out2,
                          int rb0, int rb1, int M0, int M1, int M2) {
    int idx4 = blockIdx.x * 256 + threadIdx.x;
    int row = idx4 / 96, cq = idx4 - row * 96, col = cq * 4;
    int seg = (row >= rb0) + (row >= rb1);
    int vr = row - (seg == 1 ? rb0 : seg == 2 ? rb1 : 0);
    int M = seg == 0 ? M0 : seg == 1 ? M1 : M2;
    const float* res = seg == 0 ? res0 : seg == 1 ? res1 : res2;
    float* outf = seg == 0 ? out0 : seg == 1 ? out1 : out2;
    f32x4 v = {0.f, 0.f, 0.f, 0.f};
    if (vr < M) {
        us16x4 h = ((const us16x4*)H)[idx4];
        const float* ms = mstats + seg * 768;
        f32x4 sc = *(const f32x4*)(ms + col);
        f32x4 sh = *(const f32x4*)(ms + 384 + col);
        v.x = bf2f(h.x) * sc.x + sh.x;
        v.y = bf2f(h.y) * sc.y + sh.y;
        v.z = bf2f(h.z) * sc.z + sh.z;
        v.w = bf2f(h.w) * sc.w + sh.w;
        if (res) {
            f32x4 r = ((const f32x4*)res)[(size_t)vr * 96 + cq];
            v.x += r.x; v.y += r.y; v.z += r.z; v.w += r.w;
        }
    }
    ((f32x4*)outf)[(size_t)vr * 96 + cq] = v;
}

// ---- dist[b][cs][p] = ||cls[cs]-patch[cs,p]||  (1 wave per row) ----
__global__ void dist_k(const float* __restrict__ epsP, const float* __restrict__ dpfP,
                       const float* __restrict__ supC, const float* __restrict__ dsupC,
                       float* __restrict__ dist) {
    int id = blockIdx.x;               // 0..9799
    int b = id / (CC * SS * PP);
    int r = id - b * (CC * SS * PP);   // cs*196+p
    int cs = r / PP;
    const float* patch = b ? dpfP : epsP;
    const float* cls = b ? dsupC : supC;
    int l = threadIdx.x;  // 64
    const float* pr = patch + (size_t)r * DD;
    const float* cr = cls + (size_t)cs * DD;
    float s = 0.f;
    for (int d = l; d < DD; d += 64) { float df = cr[d] - pr[d]; s += df * df; }
#pragma unroll
    for (int off = 32; off > 0; off >>= 1) s += __shfl_xor(s, off);
    if (l == 0) dist[id] = sqrtf(s);
}

// ---- enhance: sim = dist/(other+1e-6), rank-based top-30, mean of selected ----
__global__ void enh_k(const float* __restrict__ dist, const float* __restrict__ epsP,
                      const float* __restrict__ dpfP, const float* __restrict__ supC,
                      const float* __restrict__ dsupC, float* __restrict__ enh) {
    int id = blockIdx.x;          // 0..49 = b*25+cs
    int b = id / 25, cs = id - b * 25, c = cs / SS;
    int t = threadIdx.x;          // 384
    __shared__ float sim[PP];
    __shared__ int sidx[KK];
    const float* db = dist + b * (CC * SS * PP);
    if (t < PP) {
        float osum = 0.f;
        for (int cc = 0; cc < CC; ++cc) osum += db[cc * SS * PP + t];   // d0 (s=0) rows
        float other = osum - db[c * SS * PP + t];
        sim[t] = db[cs * PP + t] / (other + 1e-6f);
    }
    __syncthreads();
    if (t < PP) {
        float mine = sim[t];
        int cnt = 0;
        for (int p = 0; p < PP; ++p) {
            float v = sim[p];
            cnt += (v > mine) || (v == mine && p < t);
        }
        if (cnt < KK) sidx[cnt] = t;     // rank unique -> no race
    }
    __syncthreads();
    const float* patch = b ? dpfP : epsP;
    const float* cls = b ? dsupC : supC;
    float sum = 0.f;
#pragma unroll
    for (int j = 0; j < KK; ++j) sum += patch[((size_t)cs * PP + sidx[j]) * DD + t];
    enh[(size_t)id * DD + t] = 2.f * cls[(size_t)cs * DD + t] + sum * (1.f / 30.f);
}

// ---- ep[c] = mean over 10 enh rows; also prototype norms ----
__global__ void ep_k(const float* __restrict__ enh, float* __restrict__ outEp,
                     float* __restrict__ npb) {
    int t = threadIdx.x;  // 384
    __shared__ float red[DD];
    for (int c = 0; c < CC; ++c) {
        float v = 0.f;
        for (int b = 0; b < 2; ++b)
            for (int s = 0; s < SS; ++s)
                v += enh[((b * 25) + (c * SS + s)) * DD + t];
        v *= 0.1f;
        outEp[c * DD + t] = v;
        red[t] = v * v;
        __syncthreads();
        if (t < 64) {
            float s = 0.f;
            for (int i = t; i < DD; i += 64) s += red[i];
#pragma unroll
            for (int off = 32; off > 0; off >>= 1) s += __shfl_xor(s, off);
            if (t == 0) npb[c] = sqrtf(s);
        }
        __syncthreads();
    }
}

// ---- eB[c][row] = exp(cos(proto_c, patch_row) - 1): coalesced float4 reads ----
__global__ void cos_k(const float* __restrict__ epq, const float* __restrict__ ep,
                      const float* __restrict__ npb, float* __restrict__ eB) {
    __shared__ __align__(16) float epl[CC * DD];
    __shared__ float npl[CC];
    int t = threadIdx.x;  // 256
    for (int i = t; i < CC * DD; i += 256) epl[i] = ep[i];
    if (t < CC) npl[t] = npb[t];
    __syncthreads();
    int wid = t >> 6, l = t & 63;
    int row = blockIdx.x * 4 + wid;           // 3675*4 = 14700 exactly
    const float4* rp = (const float4*)(epq + (size_t)row * DD);
    const float4* e4 = (const float4*)epl;
    float nq = 0.f, dot[CC];
#pragma unroll
    for (int c = 0; c < CC; ++c) dot[c] = 0.f;
    for (int c4 = l; c4 < DD / 4; c4 += 64) {
        float4 x = rp[c4];
        nq += x.x * x.x + x.y * x.y + x.z * x.z + x.w * x.w;
#pragma unroll
        for (int c = 0; c < CC; ++c) {
            float4 e = e4[c * (DD / 4) + c4];
            dot[c] += e.x * x.x + e.y * x.y + e.z * x.z + e.w * x.w;
        }
    }
#pragma unroll
    for (int off = 32; off > 0; off >>= 1) {
        nq += __shfl_xor(nq, off);
#pragma unroll
        for (int c = 0; c < CC; ++c) dot[c] += __shfl_xor(dot[c], off);
    }
    if (l == 0) {
        float sq = sqrtf(nq);
#pragma unroll
        for (int c = 0; c < CC; ++c)
            eB[c * QP + row] = expf(dot[c] / fmaxf(npl[c] * sq, 1e-8f) - 1.f);
    }
}

// ---- per-(c,q): normalize e, rank-based top-30, weighted-sum gather ----
__global__ void walk2_k(const float* __restrict__ eB, const float* __restrict__ epq,
                        const float* __restrict__ qcls, float* __restrict__ outp) {
    int bid = blockIdx.x;         // c*75+q
    int c = bid / QQ, q = bid - c * QQ;
    int t = threadIdx.x;          // 256
    __shared__ float wv[PP];
    __shared__ float red[256];
    __shared__ float sval[KK];
    __shared__ int sidx[KK];
    float e = 0.f;
    if (t < PP) { e = eB[c * QP + q * PP + t]; wv[t] = e; }
    red[t] = e;
    __syncthreads();
    for (int st = 128; st > 0; st >>= 1) { if (t < st) red[t] += red[t + st]; __syncthreads(); }
    float inv = 1.f / red[0];
    if (t < PP) {
        int cnt = 0;
        for (int p = 0; p < PP; ++p) {
            float v = wv[p];
            cnt += (v > e) || (v == e && p < t);
        }
        if (cnt < KK) { sval[cnt] = e * inv; sidx[cnt] = t; }
    }
    __syncthreads();
    const float* eb = epq + (size_t)q * PP * DD;
    for (int d = t; d < DD; d += 256) {
        float a = 0.f;
#pragma unroll
        for (int j = 0; j < KK; ++j) a += sval[j] * eb[(size_t)sidx[j] * DD + d];
        outp[(size_t)bid * DD + d] = 2.f * qcls[q * DD + d] + a;
    }
}

extern "C" void kernel_launch(void* const* d_in, const int* in_sizes, int n_in,
                              void* d_out, int out_size, void* d_ws, size_t ws_size,
                              hipStream_t stream) {
    const float* sup   = (const float*)d_in[0];
    const float* qcls  = (const float*)d_in[1];
    const float* dsupI = (const float*)d_in[2];
    const float* epsI  = (const float*)d_in[3];
    const float* epqI  = (const float*)d_in[4];
    const float* dpI   = (const float*)d_in[5];
    const float* daW1 = (const float*)d_in[6],  *daG1 = (const float*)d_in[8],
               * daBe1 = (const float*)d_in[9], *daAl = (const float*)d_in[10];
    const float* daW2 = (const float*)d_in[11], *daG2 = (const float*)d_in[13],
               * daBe2 = (const float*)d_in[14];
    const float* paW1 = (const float*)d_in[15], *paG1 = (const float*)d_in[17],
               * paBe1 = (const float*)d_in[18], *paAl = (const float*)d_in[19];
    const float* paW2 = (const float*)d_in[20], *paG2 = (const float*)d_in[22],
               * paBe2 = (const float*)d_in[23];

    char* ws = (char*)d_ws;
    size_t off = 0;
    auto alloc = [&](size_t b) -> void* {
        void* p = ws + off;
        off = (off + b + 255) & ~(size_t)255;
        return p;
    };
    // row geometry (all 128-aligned so GEMM blocks stay within one segment)
    const int MP_S = 128;                  // dalle_sup: 25 valid
    const int M_P = 4900,  MP_P = 4992;    // patch batches
    const int M_Q = 14700, MP_Qa = 14848;  // query patches
    const int ROWS_A  = MP_S + MP_P;               // 5120
    const int ROWS_BC = MP_P + MP_Qa + MP_P;       // 24832
    const int RB0 = MP_P, RB1 = MP_P + MP_Qa;      // 4992, 19840

    u16*   wtAll = (u16*)alloc((size_t)4 * DD * DD * 2);
    u16*   wtDa1 = wtAll;
    u16*   wtDa2 = wtAll + DD * DD;
    u16*   wtPa1 = wtAll + 2 * DD * DD;
    u16*   wtPa2 = wtAll + 3 * DD * DD;
    u16*   hbuf  = (u16*)alloc((size_t)ROWS_BC * DD * 2);
    u16*   a2buf = (u16*)alloc((size_t)ROWS_BC * DD * 2);
    float* partial = (float*)alloc((size_t)(ROWS_BC / 128) * DD * 2 * 4);
    float* mstats  = (float*)alloc(3 * 768 * 4);
    float* dalleSup = (float*)alloc((size_t)MP_S * DD * 4);
    float* dp0   = (float*)alloc((size_t)MP_P * DD * 4);
    float* epsB  = (float*)alloc((size_t)MP_P * DD * 4);
    float* epqB  = (float*)alloc((size_t)MP_Qa * DD * 4);
    float* dpfB  = (float*)alloc((size_t)MP_P * DD * 4);
    float* distB = (float*)alloc((size_t)2 * CC * SS * PP * 4);
    float* enhB  = (float*)alloc((size_t)50 * DD * 4);
    float* npB   = (float*)alloc(64);
    float* eB    = (float*)alloc((size_t)CC * QP * 4);

    prep_w4<<<4 * 576, 256, 0, stream>>>(daW1, daW2, paW1, paW2, wtAll);

    // ---------- pass A (da): seg0 = dalle_emb_support(25), seg1 = dalle_patch(4900) ----------
    {
        int mb = ROWS_A / 128;                    // 40
        int nblk = ((mb + 7) / 8) * 24;           // 120
        SegDesc s0{0, 1, 1.f / 25.f}, s1{1, mb, 1.f / 4900.f}, sx{0, 0, 1.f};
        int g96 = (ROWS_A * 96) / 256;            // 1920
        gemmF<<<nblk, 256, 0, stream>>>(dsupI, dpI, nullptr, MP_S, ROWS_A,
                                        25, M_P, 0, wtDa1, hbuf, partial, mb);
        colfin<<<2, 384, 0, stream>>>(partial, s0, s1, sx, daG1, daBe1, mstats);
        gemmA<<<nblk, 256, 0, stream>>>(hbuf, MP_S, ROWS_A, 25, M_P, 0,
                                        wtDa2, daAl, mstats, a2buf, partial, mb);
        colfin<<<2, 384, 0, stream>>>(partial, s0, s1, sx, daG2, daBe2, mstats);
        mlp_out_k<<<g96, 256, 0, stream>>>(a2buf, mstats,
                                           nullptr, dalleSup,
                                           nullptr, dp0,
                                           nullptr, nullptr,
                                           MP_S, ROWS_A, 25, M_P, 0);
    }

    // ---------- pass BC (pa): seg0 = eps(4900), seg1 = epq(14700), seg2 = dalle_patch(4900, f32 dp0) ----------
    {
        int mb = ROWS_BC / 128;                   // 194
        int nblk = ((mb + 7) / 8) * 24;           // 600
        SegDesc s0{0, RB0 / 128, 1.f / 4900.f},
                s1{RB0 / 128, RB1 / 128, 1.f / 14700.f},
                s2{RB1 / 128, mb, 1.f / 4900.f};
        int g96 = (ROWS_BC * 96) / 256;           // 9312
        gemmF<<<nblk, 256, 0, stream>>>(epsI, epqI, dp0, RB0, RB1,
                                        M_P, M_Q, M_P, wtPa1, hbuf, partial, mb);
        colfin<<<3, 384, 0, stream>>>(partial, s0, s1, s2, paG1, paBe1, mstats);
        gemmA<<<nblk, 256, 0, stream>>>(hbuf, RB0, RB1, M_P, M_Q, M_P,
                                        wtPa2, paAl, mstats, a2buf, partial, mb);
        colfin<<<3, 384, 0, stream>>>(partial, s0, s1, s2, paG2, paBe2, mstats);
        mlp_out_k<<<g96, 256, 0, stream>>>(a2buf, mstats,
                                           epsI, epsB,
                                           epqI, epqB,
                                           dp0, dpfB,
                                           RB0, RB1, M_P, M_Q, M_P);
    }

    // ---------- enhancement ----------
    dist_k<<<2 * CC * SS * PP, 64, 0, stream>>>(epsB, dpfB, sup, dalleSup, distB);
    enh_k<<<2 * CC * SS, 384, 0, stream>>>(distB, epsB, dpfB, sup, dalleSup, enhB);

    float* outEp = (float*)d_out;
    float* outW = (float*)d_out + CC * DD;
    ep_k<<<1, 384, 0, stream>>>(enhB, outEp, npB);

    // ---------- feature walk ----------
    cos_k<<<QP / 4, 256, 0, stream>>>(epqB, outEp, npB, eB);
    walk2_k<<<CC * QQ, 256, 0, stream>>>(eB, epqB, qcls, outW);
}